// Round 10
// baseline (778.290 us; speedup 1.0000x reference)
//
#include <hip/hip_runtime.h>
#include <hip/hip_bf16.h>

#define DIM 384
#define NH 8
#define CH 48
#define NPIX 4096
#define LOGIT_MAX 4.6051701859880914f  // ln(1/0.01)

typedef unsigned int uint;
typedef __attribute__((ext_vector_type(4))) float f32x4;
typedef __attribute__((ext_vector_type(8))) short bf16x8;

union f2u { float f; uint u; };
__device__ __forceinline__ float bf_lo(uint u) { f2u t; t.u = u << 16; return t.f; }
__device__ __forceinline__ float bf_hi(uint u) { f2u t; t.u = u & 0xffff0000u; return t.f; }
__device__ __forceinline__ unsigned short bfbits(float f) {
  __hip_bfloat16 h = __float2bfloat16(f);
  return *reinterpret_cast<unsigned short*>(&h);
}

// async global->LDS, 16B per lane; dest = wave-uniform base + lane*16
__device__ __forceinline__ void gload16(const void* g, void* l) {
  using gp = const __attribute__((address_space(1))) uint*;
  using lp = __attribute__((address_space(3))) uint*;
  __builtin_amdgcn_global_load_lds((gp)(unsigned long long)g,
                                   (lp)(uint)(unsigned long long)l, 16, 0, 0);
}

// ---------------- LayerNorm (channel axis), fp32 NCHW in -> bf16 pixel-major out ---------
#define LNP 390
__global__ __launch_bounds__(256) void ln_t_kernel(const float* __restrict__ x,
                                                   const float* __restrict__ g,
                                                   const float* __restrict__ be,
                                                   __hip_bfloat16* __restrict__ out) {
  __shared__ __hip_bfloat16 T[64 * LNP];
  __shared__ float ps1[4][64], ps2[4][64], mArr[64], iArr[64];
  int b = blockIdx.y, n0 = blockIdx.x * 64;
  int nl = threadIdx.x & 63, cg = threadIdx.x >> 6;
  const float* xb = x + ((size_t)b * DIM) * NPIX + n0 + nl;
  float s1 = 0.f, s2 = 0.f;
#pragma unroll 4
  for (int i = 0; i < 96; ++i) {
    int c = cg * 96 + i;
    float v = xb[(size_t)c * NPIX];
    s1 += v; s2 += v * v;
    T[nl * LNP + c] = __float2bfloat16(v);
  }
  ps1[cg][nl] = s1; ps2[cg][nl] = s2;
  __syncthreads();
  if (threadIdx.x < 64) {
    float a = ps1[0][nl] + ps1[1][nl] + ps1[2][nl] + ps1[3][nl];
    float q = ps2[0][nl] + ps2[1][nl] + ps2[2][nl] + ps2[3][nl];
    float m = a * (1.f / DIM);
    float var = q * (1.f / DIM) - m * m;
    mArr[nl] = m;
    iArr[nl] = rsqrtf(var + 1e-5f);
  }
  __syncthreads();
  float m = mArr[nl], inv = iArr[nl];
#pragma unroll 4
  for (int i = 0; i < 96; ++i) {
    int c = cg * 96 + i;
    float v = __bfloat162float(T[nl * LNP + c]);
    v = (v - m) * inv * g[c] + be[c];
    T[nl * LNP + c] = __float2bfloat16(v);
  }
  __syncthreads();
  uint* ob = (uint*)(out + ((size_t)b * NPIX + n0) * DIM);
#pragma unroll 4
  for (int it = 0; it < 48; ++it) {
    int gi = it * 256 + threadIdx.x;   // dword index in 64x384 tile
    int n = gi / 192, c2 = gi % 192;
    uint w = *(const uint*)((const char*)T + n * (LNP * 2) + c2 * 4);
    ob[gi] = w;
  }
}

// ---------------- MFMA GEMM: 128x128 tile, BK=32, 4 waves --------------------------------
// 4-buffer rotation, 3 tiles in flight, counted vmcnt(8)/4/0; ONE barrier per k-step;
// LDS-staged coalesced epilogue for PIX=1 (XOR-swizzled C-tile).
// PIX=1: out bf16 pixel-major [b][ON][O] (A=W rows=o, B=X rows=n)
// PIX=0: out fp32 channel-major [b][O][4096] (+Res) (A=X rows=n, B=W rows=o)
template <int PIX, int GELU_ACT, int RES>
__global__ __launch_bounds__(256) void mfma_gemm(const __hip_bfloat16* __restrict__ Wb,
                                                 const float* __restrict__ bias,
                                                 const __hip_bfloat16* __restrict__ X,
                                                 int XN, int xn0,
                                                 void* __restrict__ outp, int ON, int on0,
                                                 const float* __restrict__ Res, int O, int K) {
  // 4 buffers x (W 4096 | X 4096) bf16 = 64 KiB; epilogue reuses 34816 B of it
  __shared__ alignas(16) __hip_bfloat16 smem[4 * 8192];
  const int b = blockIdx.z;
  const int n0 = blockIdx.x * 128, o0 = blockIdx.y * 128;
  const int tid = threadIdx.x, lane = tid & 63, wv = tid >> 6;
  const int srow = lane >> 2;                            // 0..15 row within chunk
  const int ksl = ((lane & 3) ^ ((srow >> 1) & 3)) * 8;  // pre-swizzled k-octet
  const __hip_bfloat16* srcW = Wb + (size_t)(o0 + wv * 32 + srow) * K + ksl;
  const __hip_bfloat16* srcX = X + ((size_t)b * XN + xn0 + n0 + wv * 32 + srow) * K + ksl;
  f32x4 acc[4][4];
#pragma unroll
  for (int i = 0; i < 4; ++i)
#pragma unroll
    for (int j = 0; j < 4; ++j) acc[i][j] = {0.f, 0.f, 0.f, 0.f};
  const int lrow = lane & 15, ko = lane >> 4;
  const int swz = ko ^ ((lrow >> 1) & 3);
  const int wr0 = (wv >> 1) * 64, wc0 = (wv & 1) * 64;

  auto STAGE = [&](int buf, int k0) {
    __hip_bfloat16* base = smem + buf * 8192 + wv * 1024;
    gload16(srcW + k0, base);
    gload16(srcW + (size_t)16 * K + k0, base + 512);
    gload16(srcX + k0, base + 4096);
    gload16(srcX + (size_t)16 * K + k0, base + 4096 + 512);
  };
  auto COMPUTE = [&](int buf) {
    const bf16x8* lAv = (const bf16x8*)(smem + buf * 8192 + (PIX ? 0 : 4096));
    const bf16x8* lBv = (const bf16x8*)(smem + buf * 8192 + (PIX ? 4096 : 0));
    bf16x8 af[4], bfv[4];
#pragma unroll
    for (int i = 0; i < 4; ++i) af[i] = lAv[(wr0 + i * 16 + lrow) * 4 + swz];
#pragma unroll
    for (int j = 0; j < 4; ++j) bfv[j] = lBv[(wc0 + j * 16 + lrow) * 4 + swz];
#pragma unroll
    for (int i = 0; i < 4; ++i)
#pragma unroll
      for (int j = 0; j < 4; ++j)
        acc[i][j] = __builtin_amdgcn_mfma_f32_16x16x32_bf16(af[i], bfv[j], acc[i][j], 0, 0, 0);
  };

  const int nk = K >> 5;                 // 12 or 48
  STAGE(0, 0);
  STAGE(1, 32);
  STAGE(2, 64);
  for (int t = 0; t < nk; ++t) {
    int rem = nk - t;                    // tiles t..t+min(rem,3)-1 are in flight
    if (rem >= 3) {
      asm volatile("s_waitcnt vmcnt(8)" ::: "memory");
    } else if (rem == 2) {
      asm volatile("s_waitcnt vmcnt(4)" ::: "memory");
    } else {
      asm volatile("s_waitcnt vmcnt(0)" ::: "memory");
    }
    __builtin_amdgcn_s_barrier();        // tile t visible to all; buf (t-1)&3 free
    if (t + 3 < nk) STAGE((t + 3) & 3, (t + 3) * 32);
    COMPUTE(t & 3);
  }

  if (PIX) {
    // stage C in LDS ([128 n][136 o] bf16, o XOR-swizzled by (n&7)<<4) then coalesced stores
    __syncthreads();
#pragma unroll
    for (int i = 0; i < 4; ++i) {
      int o_l = wr0 + i * 16 + ko * 4;
      int og = o0 + o_l;
      float bv[4] = {bias[og], bias[og + 1], bias[og + 2], bias[og + 3]};
#pragma unroll
      for (int j = 0; j < 4; ++j) {
        int n_l = wc0 + j * 16 + lrow;
        float v[4];
#pragma unroll
        for (int r = 0; r < 4; ++r) {
          v[r] = acc[i][j][r] + bv[r];
          if (GELU_ACT) v[r] = v[r] * 0.5f * (1.f + erff(v[r] * 0.70710678118f));
        }
        int oS = o_l ^ ((n_l & 7) << 4);
        *(ushort4*)&smem[n_l * 136 + oS] =
            make_ushort4(bfbits(v[0]), bfbits(v[1]), bfbits(v[2]), bfbits(v[3]));
      }
    }
    __syncthreads();
    __hip_bfloat16* ob = (__hip_bfloat16*)outp + ((size_t)b * ON + on0 + n0) * O + o0;
#pragma unroll
    for (int it = 0; it < 8; ++it) {
      int gi = it * 256 + tid;
      int n = gi >> 4, c = gi & 15;     // 16 lanes -> 256B contiguous per row
      uint4 wq = *(const uint4*)&smem[n * 136 + ((c * 8) ^ ((n & 7) << 4))];
      *(uint4*)(ob + (size_t)n * O + c * 8) = wq;
    }
  } else {
    float* of = (float*)outp;
#pragma unroll
    for (int i = 0; i < 4; ++i) {
      int nb0 = on0 + n0 + wr0 + i * 16 + ko * 4;
#pragma unroll
      for (int j = 0; j < 4; ++j) {
        int o = o0 + wc0 + j * 16 + lrow;
        size_t idx = ((size_t)b * O + o) * 4096 + nb0;
        float bv = bias[o];
        float4 w;
        w.x = acc[i][j][0] + bv; w.y = acc[i][j][1] + bv;
        w.z = acc[i][j][2] + bv; w.w = acc[i][j][3] + bv;
        if (RES) {
          const float4 rr = *(const float4*)&Res[idx];
          w.x += rr.x; w.y += rr.y; w.z += rr.z; w.w += rr.w;
        }
        *(float4*)&of[idx] = w;
      }
    }
  }
}

// ---------------- QK stage A: per-chunk 48x48 score partials + channel sumsq -------------
// grid (8 chunks, 128 bl); each block handles 512 pixels of one (b,head).
__global__ __launch_bounds__(256) void qk_a(const __hip_bfloat16* __restrict__ qkv,
                                            float* __restrict__ ps,   // [128][8][2304]
                                            float* __restrict__ pss)  // [128][8][96]
{
  __shared__ float T[64][100];
  __shared__ float ssq_red[192];
  int bl = blockIdx.y, b = bl >> 3, lh = bl & 7;
  int chunk = blockIdx.x;
  int tid = threadIdx.x;
  int i0 = (tid >> 4) * 3, j0 = (tid & 15) * 3;
  int ch = tid % 96, ph = tid / 96;  // sumsq assignment (ph==2 -> idle for sumsq)
  float s[3][3] = {};
  float ssq = 0.f;
  for (int sub = 0; sub < 8; ++sub) {
    int nc = chunk * 512 + sub * 64;
    __syncthreads();
#pragma unroll
    for (int it = 0; it < 3; ++it) {
      int q = it * 256 + tid;
      int row = q / 12, part = q % 12;
      uint4 u = *(const uint4*)(qkv + ((size_t)b * NPIX + nc + row) * 1152 + lh * 144 + part * 8);
      float* tp = &T[row][part * 8];
      tp[0] = bf_lo(u.x); tp[1] = bf_hi(u.x); tp[2] = bf_lo(u.y); tp[3] = bf_hi(u.y);
      tp[4] = bf_lo(u.z); tp[5] = bf_hi(u.z); tp[6] = bf_lo(u.w); tp[7] = bf_hi(u.w);
    }
    __syncthreads();
#pragma unroll 4
    for (int n = 0; n < 64; ++n) {
      float qa0 = T[n][i0], qa1 = T[n][i0 + 1], qa2 = T[n][i0 + 2];
      float kb0 = T[n][48 + j0], kb1 = T[n][48 + j0 + 1], kb2 = T[n][48 + j0 + 2];
      s[0][0] += qa0 * kb0; s[0][1] += qa0 * kb1; s[0][2] += qa0 * kb2;
      s[1][0] += qa1 * kb0; s[1][1] += qa1 * kb1; s[1][2] += qa1 * kb2;
      s[2][0] += qa2 * kb0; s[2][1] += qa2 * kb1; s[2][2] += qa2 * kb2;
    }
    if (ph < 2) {
#pragma unroll 8
      for (int px = ph * 32; px < ph * 32 + 32; ++px) {
        float v = T[px][ch];
        ssq += v * v;
      }
    }
  }
  float* sp = ps + ((size_t)bl * 8 + chunk) * 2304;
#pragma unroll
  for (int a = 0; a < 3; ++a)
#pragma unroll
    for (int bb = 0; bb < 3; ++bb) sp[(i0 + a) * 48 + j0 + bb] = s[a][bb];
  __syncthreads();
  if (ph < 2) ssq_red[ph * 96 + ch] = ssq;
  __syncthreads();
  if (tid < 96) pss[((size_t)bl * 8 + chunk) * 96 + tid] = ssq_red[tid] + ssq_red[96 + tid];
}

// ---------------- QK stage B: merge partials, normalize, softmax -> attn bf16 ------------
__global__ __launch_bounds__(256) void qk_b(const float* __restrict__ ps,
                                            const float* __restrict__ pss,
                                            const float* __restrict__ lsc,
                                            __hip_bfloat16* __restrict__ attn_bf) {
  __shared__ float inv_s[96];
  __shared__ float S[2304];
  int bl = blockIdx.x, lh = bl & 7;
  int tid = threadIdx.x;
  if (tid < 96) {
    float s = 0.f;
#pragma unroll
    for (int c = 0; c < 8; ++c) s += pss[((size_t)bl * 8 + c) * 96 + tid];
    inv_s[tid] = 1.f / fmaxf(sqrtf(s), 1e-12f);
  }
  __syncthreads();
  float scale = expf(fminf(lsc[lh], LOGIT_MAX));
#pragma unroll
  for (int r = 0; r < 9; ++r) {
    int e = r * 256 + tid;
    float s = 0.f;
#pragma unroll
    for (int c = 0; c < 8; ++c) s += ps[((size_t)bl * 8 + c) * 2304 + e];
    int i = e / 48, j = e % 48;
    S[e] = s * inv_s[i] * inv_s[48 + j] * scale;
  }
  __syncthreads();
  if (tid < 48) {
    int i = tid;
    float mx = -1e30f;
    for (int j = 0; j < 48; ++j) mx = fmaxf(mx, S[i * 48 + j]);
    float sum = 0.f;
    for (int j = 0; j < 48; ++j) {
      float ev = expf(S[i * 48 + j] - mx);
      S[i * 48 + j] = ev;
      sum += ev;
    }
    float r = 1.f / sum;
    __hip_bfloat16* ap = attn_bf + (size_t)bl * 3072 + i * 64;
    for (int j = 0; j < 48; ++j) ap[j] = __float2bfloat16(S[i * 48 + j] * r);
    for (int j = 48; j < 64; ++j) ap[j] = __float2bfloat16(0.f);
  }
}

// ---------------- A·V via MFMA: aout[b][n][lh*48+c] = sum_d attn[c][d] v[n][d] -----------
__global__ __launch_bounds__(256) void av_mfma(const __hip_bfloat16* __restrict__ attn_bf,
                                               const __hip_bfloat16* __restrict__ qkv,
                                               __hip_bfloat16* __restrict__ aout,
                                               const __hip_bfloat16* __restrict__ zb) {
  __shared__ alignas(16) __hip_bfloat16 la[3072];  // attn [48][64], slot^=(row&7)
  __shared__ alignas(16) __hip_bfloat16 lv[8192];  // V [128 n][64 d], slot^=(row&7)
  int bl = blockIdx.y, b = bl >> 3, lh = bl & 7;
  int n0 = blockIdx.x * 128;
  int tid = threadIdx.x, lane = tid & 63, wv = tid >> 6;
  {
    int r = lane >> 3, sl = lane & 7;
    for (int c = wv; c < 6; c += 4) {  // attn: 6 chunks of 8 rows
      int row = c * 8 + r;
      int sp = sl ^ (row & 7);
      gload16(attn_bf + (size_t)bl * 3072 + row * 64 + sp * 8, la + c * 512);
    }
#pragma unroll
    for (int i = 0; i < 4; ++i) {  // V: 16 chunks of 8 rows
      int c = wv * 4 + i;
      int row = c * 8 + r;
      int sp = sl ^ (row & 7);
      const __hip_bfloat16* src =
          (sp < 6) ? qkv + ((size_t)b * NPIX + n0 + row) * 1152 + lh * 144 + 96 + sp * 8 : zb;
      gload16(src, lv + c * 512);
    }
  }
  __syncthreads();
  int lrow = lane & 15, ko = lane >> 4;
  f32x4 acc[3][2];
#pragma unroll
  for (int cf = 0; cf < 3; ++cf)
#pragma unroll
    for (int nf = 0; nf < 2; ++nf) acc[cf][nf] = {0.f, 0.f, 0.f, 0.f};
  const bf16x8* lav = (const bf16x8*)la;
  const bf16x8* lvv = (const bf16x8*)lv;
#pragma unroll
  for (int ks = 0; ks < 2; ++ks) {
    bf16x8 a[3], vb[2];
#pragma unroll
    for (int cf = 0; cf < 3; ++cf) {
      int c = cf * 16 + lrow;
      a[cf] = lav[c * 8 + ((ks * 4 + ko) ^ (c & 7))];
    }
#pragma unroll
    for (int nf = 0; nf < 2; ++nf) {
      int n = wv * 32 + nf * 16 + lrow;
      vb[nf] = lvv[n * 8 + ((ks * 4 + ko) ^ (n & 7))];
    }
#pragma unroll
    for (int cf = 0; cf < 3; ++cf)
#pragma unroll
      for (int nf = 0; nf < 2; ++nf)
        acc[cf][nf] = __builtin_amdgcn_mfma_f32_16x16x32_bf16(a[cf], vb[nf], acc[cf][nf], 0, 0, 0);
  }
#pragma unroll
  for (int cf = 0; cf < 3; ++cf)
#pragma unroll
    for (int nf = 0; nf < 2; ++nf) {
      int n = n0 + wv * 32 + nf * 16 + lrow;
      int c = cf * 16 + ko * 4;
      *(ushort4*)(aout + ((size_t)b * NPIX + n) * DIM + lh * CH + c) =
          make_ushort4(bfbits(acc[cf][nf][0]), bfbits(acc[cf][nf][1]),
                       bfbits(acc[cf][nf][2]), bfbits(acc[cf][nf][3]));
    }
}

// ---------------- fp32 -> bf16 weight conversion (vec4) ----------------------------------
__global__ __launch_bounds__(256) void wcvt4(const float* __restrict__ w,
                                             __hip_bfloat16* __restrict__ o, int n4) {
  int i = blockIdx.x * 256 + threadIdx.x;
  if (i >= n4) return;
  float4 v = ((const float4*)w)[i];
  ((ushort4*)o)[i] = make_ushort4(bfbits(v.x), bfbits(v.y), bfbits(v.z), bfbits(v.w));
}

extern "C" void kernel_launch(void* const* d_in, const int* in_sizes, int n_in,
                              void* d_out, int out_size, void* d_ws, size_t ws_size,
                              hipStream_t stream) {
  (void)in_sizes; (void)n_in; (void)out_size; (void)ws_size;
  const float* x      = (const float*)d_in[0];
  const float* g1     = (const float*)d_in[1];
  const float* beta1  = (const float*)d_in[2];
  const float* w_qkv  = (const float*)d_in[3];
  const float* b_qkv  = (const float*)d_in[4];
  const float* lsc    = (const float*)d_in[5];
  const float* w_proj = (const float*)d_in[6];
  const float* b_proj = (const float*)d_in[7];
  const float* g2     = (const float*)d_in[8];
  const float* beta2  = (const float*)d_in[9];
  const float* w_ffn1 = (const float*)d_in[10];
  const float* b_ffn1 = (const float*)d_in[11];
  const float* w_ffn2 = (const float*)d_in[12];
  const float* b_ffn2 = (const float*)d_in[13];
  float* out = (float*)d_out;

  // arena (pixel-major bf16 intermediates), max used = 252,788,992 B
  char* ws = (char*)d_ws;
  __hip_bfloat16* xn     = (__hip_bfloat16*)(ws);                 // [16][4096][384] (also yn)
  __hip_bfloat16* qkv    = (__hip_bfloat16*)(ws + 50331648ull);   // [16][4096][1152]
  __hip_bfloat16* hbuf   = (__hip_bfloat16*)(ws + 50331648ull);   // [16][2048][1536] (FFN phase)
  __hip_bfloat16* wffn1b = (__hip_bfloat16*)(ws + 151000064ull);  // converted after AV
  __hip_bfloat16* wffn2b = (__hip_bfloat16*)(ws + 152179712ull);
  __hip_bfloat16* aout   = (__hip_bfloat16*)(ws + 201326592ull);  // [16][4096][384]
  __hip_bfloat16* wqkvb  = (__hip_bfloat16*)(ws + 201326592ull);  // early phase (pre-QK)
  float*          ps     = (float*)(ws + 201326592ull);           // [128][8][2304] (post-QKV)
  float*          pss    = (float*)(ws + 210763776ull);           // [128][8][96]
  const size_t T0 = 251658240ull;
  __hip_bfloat16* attnb  = (__hip_bfloat16*)(ws + T0 + 49152ull); // [128][48][64]
  __hip_bfloat16* zb     = (__hip_bfloat16*)(ws + T0 + 835584ull);// 256B zeros
  __hip_bfloat16* wprojb = (__hip_bfloat16*)(ws + T0 + 835840ull);

  (void)hipMemsetAsync(zb, 0, 256, stream);
  wcvt4<<<432, 256, 0, stream>>>(w_qkv, wqkvb, 110592);
  wcvt4<<<144, 256, 0, stream>>>(w_proj, wprojb, 36864);

  // branch 1: channel attention
  ln_t_kernel<<<dim3(64, 16), 256, 0, stream>>>(x, g1, beta1, xn);
  mfma_gemm<1, 0, 0><<<dim3(32, 9, 16), 256, 0, stream>>>(wqkvb, b_qkv, xn, 4096, 0,
                                                          qkv, 4096, 0, nullptr, 1152, 384);
  qk_a<<<dim3(8, 128), 256, 0, stream>>>(qkv, ps, pss);
  qk_b<<<128, 256, 0, stream>>>(ps, pss, lsc, attnb);
  av_mfma<<<dim3(32, 128), 256, 0, stream>>>(attnb, qkv, aout, zb);
  mfma_gemm<0, 0, 1><<<dim3(32, 3, 16), 256, 0, stream>>>(wprojb, b_proj, aout, 4096, 0,
                                                          d_out, 4096, 0, x, 384, 384);

  // branch 2: FFN (two n-halves to shrink hbuf)
  wcvt4<<<576, 256, 0, stream>>>(w_ffn1, wffn1b, 147456);
  wcvt4<<<576, 256, 0, stream>>>(w_ffn2, wffn2b, 147456);
  ln_t_kernel<<<dim3(64, 16), 256, 0, stream>>>(out, g2, beta2, xn);  // yn
  for (int h = 0; h < 2; ++h) {
    mfma_gemm<1, 1, 0><<<dim3(16, 12, 16), 256, 0, stream>>>(wffn1b, b_ffn1, xn, 4096, h * 2048,
                                                             hbuf, 2048, 0, nullptr, 1536, 384);
    mfma_gemm<0, 0, 1><<<dim3(16, 3, 16), 256, 0, stream>>>(wffn2b, b_ffn2, hbuf, 2048, 0,
                                                            d_out, 4096, h * 2048, (const float*)out,
                                                            384, 1536);
  }
}

// Round 11
// 722.346 us; speedup vs baseline: 1.0774x; 1.0774x over previous
//
#include <hip/hip_runtime.h>
#include <hip/hip_bf16.h>

#define DIM 384
#define NH 8
#define CH 48
#define NPIX 4096
#define LOGIT_MAX 4.6051701859880914f  // ln(1/0.01)

typedef unsigned int uint;
typedef __attribute__((ext_vector_type(4))) float f32x4;
typedef __attribute__((ext_vector_type(8))) short bf16x8;

union f2u { float f; uint u; };
__device__ __forceinline__ float bf_lo(uint u) { f2u t; t.u = u << 16; return t.f; }
__device__ __forceinline__ float bf_hi(uint u) { f2u t; t.u = u & 0xffff0000u; return t.f; }
__device__ __forceinline__ unsigned short bfbits(float f) {
  __hip_bfloat16 h = __float2bfloat16(f);
  return *reinterpret_cast<unsigned short*>(&h);
}

// async global->LDS, 16B per lane; dest = wave-uniform base + lane*16
__device__ __forceinline__ void gload16(const void* g, void* l) {
  using gp = const __attribute__((address_space(1))) uint*;
  using lp = __attribute__((address_space(3))) uint*;
  __builtin_amdgcn_global_load_lds((gp)(unsigned long long)g,
                                   (lp)(uint)(unsigned long long)l, 16, 0, 0);
}

// fast GELU (tanh form, via exp): 0.5x(1+tanh(.79788(x+.044715x^3))) = x/(1+e^{-2s})
__device__ __forceinline__ float gelu_fast(float x) {
  float z = -1.5957691216057308f * (x + 0.044715f * x * x * x);
  return x / (1.f + __expf(z));
}

// ---------------- LayerNorm (channel axis), fp32 NCHW in -> bf16 pixel-major out ---------
#define LNP 390
__global__ __launch_bounds__(256) void ln_t_kernel(const float* __restrict__ x,
                                                   const float* __restrict__ g,
                                                   const float* __restrict__ be,
                                                   __hip_bfloat16* __restrict__ out) {
  __shared__ __hip_bfloat16 T[64 * LNP];
  __shared__ float ps1[4][64], ps2[4][64], mArr[64], iArr[64];
  int b = blockIdx.y, n0 = blockIdx.x * 64;
  int nl = threadIdx.x & 63, cg = threadIdx.x >> 6;
  const float* xb = x + ((size_t)b * DIM) * NPIX + n0 + nl;
  float s1 = 0.f, s2 = 0.f;
#pragma unroll 4
  for (int i = 0; i < 96; ++i) {
    int c = cg * 96 + i;
    float v = xb[(size_t)c * NPIX];
    s1 += v; s2 += v * v;
    T[nl * LNP + c] = __float2bfloat16(v);
  }
  ps1[cg][nl] = s1; ps2[cg][nl] = s2;
  __syncthreads();
  if (threadIdx.x < 64) {
    float a = ps1[0][nl] + ps1[1][nl] + ps1[2][nl] + ps1[3][nl];
    float q = ps2[0][nl] + ps2[1][nl] + ps2[2][nl] + ps2[3][nl];
    float m = a * (1.f / DIM);
    float var = q * (1.f / DIM) - m * m;
    mArr[nl] = m;
    iArr[nl] = rsqrtf(var + 1e-5f);
  }
  __syncthreads();
  float m = mArr[nl], inv = iArr[nl];
#pragma unroll 4
  for (int i = 0; i < 96; ++i) {
    int c = cg * 96 + i;
    float v = __bfloat162float(T[nl * LNP + c]);
    v = (v - m) * inv * g[c] + be[c];
    T[nl * LNP + c] = __float2bfloat16(v);
  }
  __syncthreads();
  uint* ob = (uint*)(out + ((size_t)b * NPIX + n0) * DIM);
#pragma unroll 4
  for (int it = 0; it < 48; ++it) {
    int gi = it * 256 + threadIdx.x;   // dword index in 64x384 tile
    int n = gi / 192, c2 = gi % 192;
    uint w = *(const uint*)((const char*)T + n * (LNP * 2) + c2 * 4);
    ob[gi] = w;
  }
}

// ---------------- MFMA GEMM: 128x128 tile, BK=32, 4 waves --------------------------------
// 3-buffer rotation, counted vmcnt(4), ONE barrier per k-step; LDS-staged coalesced
// epilogues for BOTH output modes. nk = K/32 divisible by 3 (K=384 or 1536 here).
// PIX=1: out bf16 pixel-major [b][ON][O] (A=W rows=o, B=X rows=n)
// PIX=0: out fp32 channel-major [b][O][4096] (+Res) (A=X rows=n, B=W rows=o)
template <int PIX, int GELU_ACT, int RES>
__global__ __launch_bounds__(256) void mfma_gemm(const __hip_bfloat16* __restrict__ Wb,
                                                 const float* __restrict__ bias,
                                                 const __hip_bfloat16* __restrict__ X,
                                                 int XN, int xn0,
                                                 void* __restrict__ outp, int ON, int on0,
                                                 const float* __restrict__ Res, int O, int K) {
  // 3 buffers x (W 4096 | X 4096) bf16 = 48 KiB; epilogues reuse the space afterwards
  __shared__ alignas(16) __hip_bfloat16 smem[3 * 8192];
  const int b = blockIdx.z;
  const int n0 = blockIdx.x * 128, o0 = blockIdx.y * 128;
  const int tid = threadIdx.x, lane = tid & 63, wv = tid >> 6;
  const int srow = lane >> 2;                            // 0..15 row within chunk
  const int ksl = ((lane & 3) ^ ((srow >> 1) & 3)) * 8;  // pre-swizzled k-octet
  const __hip_bfloat16* srcW = Wb + (size_t)(o0 + wv * 32 + srow) * K + ksl;
  const __hip_bfloat16* srcX = X + ((size_t)b * XN + xn0 + n0 + wv * 32 + srow) * K + ksl;
  f32x4 acc[4][4];
#pragma unroll
  for (int i = 0; i < 4; ++i)
#pragma unroll
    for (int j = 0; j < 4; ++j) acc[i][j] = {0.f, 0.f, 0.f, 0.f};
  const int lrow = lane & 15, ko = lane >> 4;
  const int swz = ko ^ ((lrow >> 1) & 3);
  const int wr0 = (wv >> 1) * 64, wc0 = (wv & 1) * 64;

  auto STAGE = [&](int buf, int k0) {
    __hip_bfloat16* base = smem + buf * 8192 + wv * 1024;
    gload16(srcW + k0, base);
    gload16(srcW + (size_t)16 * K + k0, base + 512);
    gload16(srcX + k0, base + 4096);
    gload16(srcX + (size_t)16 * K + k0, base + 4096 + 512);
  };
  auto COMPUTE = [&](int buf) {
    const bf16x8* lAv = (const bf16x8*)(smem + buf * 8192 + (PIX ? 0 : 4096));
    const bf16x8* lBv = (const bf16x8*)(smem + buf * 8192 + (PIX ? 4096 : 0));
    bf16x8 af[4], bfv[4];
#pragma unroll
    for (int i = 0; i < 4; ++i) af[i] = lAv[(wr0 + i * 16 + lrow) * 4 + swz];
#pragma unroll
    for (int j = 0; j < 4; ++j) bfv[j] = lBv[(wc0 + j * 16 + lrow) * 4 + swz];
#pragma unroll
    for (int i = 0; i < 4; ++i)
#pragma unroll
      for (int j = 0; j < 4; ++j)
        acc[i][j] = __builtin_amdgcn_mfma_f32_16x16x32_bf16(af[i], bfv[j], acc[i][j], 0, 0, 0);
  };
  auto FULL = [&](int t, int cb, int sb) {   // steady-state iter: stage t+2, compute t
    asm volatile("s_waitcnt vmcnt(4)" ::: "memory");
    __builtin_amdgcn_s_barrier();
    STAGE(sb, (t + 2) * 32);
    COMPUTE(cb);
  };

  const int nk = K >> 5;                 // 12 or 48 — divisible by 3
  STAGE(0, 0);
  STAGE(1, 32);
  int t = 0;
  for (; t + 3 < nk; t += 3) {
    FULL(t, 0, 2); FULL(t + 1, 1, 0); FULL(t + 2, 2, 1);
  }
  FULL(nk - 3, 0, 2);                    // stages tile nk-1
  asm volatile("s_waitcnt vmcnt(4)" ::: "memory");
  __builtin_amdgcn_s_barrier();
  COMPUTE(1);
  asm volatile("s_waitcnt vmcnt(0)" ::: "memory");
  __builtin_amdgcn_s_barrier();
  COMPUTE(2);

  if (PIX) {
    // stage C in LDS ([128 n][136 o] bf16, 272B row) then fully-coalesced 16B stores
    __syncthreads();
#pragma unroll
    for (int i = 0; i < 4; ++i) {
      int o_l = wr0 + i * 16 + ko * 4;
      int og = o0 + o_l;
      float bv[4] = {bias[og], bias[og + 1], bias[og + 2], bias[og + 3]};
#pragma unroll
      for (int j = 0; j < 4; ++j) {
        int n_l = wc0 + j * 16 + lrow;
        float v[4];
#pragma unroll
        for (int r = 0; r < 4; ++r) {
          v[r] = acc[i][j][r] + bv[r];
          if (GELU_ACT) v[r] = gelu_fast(v[r]);
        }
        *(ushort4*)&smem[n_l * 136 + o_l] =
            make_ushort4(bfbits(v[0]), bfbits(v[1]), bfbits(v[2]), bfbits(v[3]));
      }
    }
    __syncthreads();
    __hip_bfloat16* ob = (__hip_bfloat16*)outp + ((size_t)b * ON + on0 + n0) * O + o0;
#pragma unroll
    for (int it = 0; it < 8; ++it) {
      int gi = it * 256 + tid;
      int n = gi >> 4, c = gi & 15;     // 16 lanes -> 256B contiguous per row
      uint4 wq = *(const uint4*)&smem[n * 136 + c * 8];
      *(uint4*)(ob + (size_t)n * O + c * 8) = wq;
    }
  } else {
    // fp32 C-tile staged via LDS in two 64-o-row halves -> coalesced stores + Res reads
    float* of = (float*)outp;
    float* T = (float*)smem;             // [64 o][132 n] fp32 = 33792 B
#pragma unroll
    for (int h = 0; h < 2; ++h) {
      __syncthreads();
      if ((wv & 1) == h) {               // this wave owns o in [h*64, h*64+64)
#pragma unroll
        for (int i = 0; i < 4; ++i) {
          int n_l = wr0 + i * 16 + ko * 4;   // n within 128 (4 consecutive via regs)
#pragma unroll
          for (int j = 0; j < 4; ++j) {
            int o_l = j * 16 + lrow;         // o within this 64-half
            *(f32x4*)&T[o_l * 132 + n_l] = acc[i][j];
          }
        }
      }
      __syncthreads();
#pragma unroll
      for (int it = 0; it < 8; ++it) {
        int gi = it * 256 + tid;            // 2048 float4 = 64 rows x 32
        int o_l = gi >> 5, nf = gi & 31;    // 32 lanes -> 512B contiguous per row
        float4 w = *(const float4*)&T[o_l * 132 + nf * 4];
        int o = o0 + h * 64 + o_l;
        size_t idx = ((size_t)b * O + o) * 4096 + on0 + n0 + nf * 4;
        float bv = bias[o];
        w.x += bv; w.y += bv; w.z += bv; w.w += bv;
        if (RES) {
          const float4 rr = *(const float4*)&Res[idx];
          w.x += rr.x; w.y += rr.y; w.z += rr.z; w.w += rr.w;
        }
        *(float4*)&of[idx] = w;
      }
    }
  }
}

// ---------------- QK stage A: per-chunk 48x48 score partials + channel sumsq -------------
// grid (8 chunks, 128 bl); each block handles 512 pixels of one (b,head).
__global__ __launch_bounds__(256) void qk_a(const __hip_bfloat16* __restrict__ qkv,
                                            float* __restrict__ ps,   // [128][8][2304]
                                            float* __restrict__ pss)  // [128][8][96]
{
  __shared__ float T[64][100];
  __shared__ float ssq_red[192];
  int bl = blockIdx.y, b = bl >> 3, lh = bl & 7;
  int chunk = blockIdx.x;
  int tid = threadIdx.x;
  int i0 = (tid >> 4) * 3, j0 = (tid & 15) * 3;
  int ch = tid % 96, ph = tid / 96;  // sumsq assignment (ph==2 -> idle for sumsq)
  float s[3][3] = {};
  float ssq = 0.f;
  for (int sub = 0; sub < 8; ++sub) {
    int nc = chunk * 512 + sub * 64;
    __syncthreads();
#pragma unroll
    for (int it = 0; it < 3; ++it) {
      int q = it * 256 + tid;
      int row = q / 12, part = q % 12;
      uint4 u = *(const uint4*)(qkv + ((size_t)b * NPIX + nc + row) * 1152 + lh * 144 + part * 8);
      float* tp = &T[row][part * 8];
      tp[0] = bf_lo(u.x); tp[1] = bf_hi(u.x); tp[2] = bf_lo(u.y); tp[3] = bf_hi(u.y);
      tp[4] = bf_lo(u.z); tp[5] = bf_hi(u.z); tp[6] = bf_lo(u.w); tp[7] = bf_hi(u.w);
    }
    __syncthreads();
#pragma unroll 4
    for (int n = 0; n < 64; ++n) {
      float qa0 = T[n][i0], qa1 = T[n][i0 + 1], qa2 = T[n][i0 + 2];
      float kb0 = T[n][48 + j0], kb1 = T[n][48 + j0 + 1], kb2 = T[n][48 + j0 + 2];
      s[0][0] += qa0 * kb0; s[0][1] += qa0 * kb1; s[0][2] += qa0 * kb2;
      s[1][0] += qa1 * kb0; s[1][1] += qa1 * kb1; s[1][2] += qa1 * kb2;
      s[2][0] += qa2 * kb0; s[2][1] += qa2 * kb1; s[2][2] += qa2 * kb2;
    }
    if (ph < 2) {
#pragma unroll 8
      for (int px = ph * 32; px < ph * 32 + 32; ++px) {
        float v = T[px][ch];
        ssq += v * v;
      }
    }
  }
  float* sp = ps + ((size_t)bl * 8 + chunk) * 2304;
#pragma unroll
  for (int a = 0; a < 3; ++a)
#pragma unroll
    for (int bb = 0; bb < 3; ++bb) sp[(i0 + a) * 48 + j0 + bb] = s[a][bb];
  __syncthreads();
  if (ph < 2) ssq_red[ph * 96 + ch] = ssq;
  __syncthreads();
  if (tid < 96) pss[((size_t)bl * 8 + chunk) * 96 + tid] = ssq_red[tid] + ssq_red[96 + tid];
}

// ---------------- QK stage B: merge partials, normalize, softmax -> attn bf16 ------------
__global__ __launch_bounds__(256) void qk_b(const float* __restrict__ ps,
                                            const float* __restrict__ pss,
                                            const float* __restrict__ lsc,
                                            __hip_bfloat16* __restrict__ attn_bf) {
  __shared__ float inv_s[96];
  __shared__ float S[2304];
  int bl = blockIdx.x, lh = bl & 7;
  int tid = threadIdx.x;
  if (tid < 96) {
    float s = 0.f;
#pragma unroll
    for (int c = 0; c < 8; ++c) s += pss[((size_t)bl * 8 + c) * 96 + tid];
    inv_s[tid] = 1.f / fmaxf(sqrtf(s), 1e-12f);
  }
  __syncthreads();
  float scale = expf(fminf(lsc[lh], LOGIT_MAX));
#pragma unroll
  for (int r = 0; r < 9; ++r) {
    int e = r * 256 + tid;
    float s = 0.f;
#pragma unroll
    for (int c = 0; c < 8; ++c) s += ps[((size_t)bl * 8 + c) * 2304 + e];
    int i = e / 48, j = e % 48;
    S[e] = s * inv_s[i] * inv_s[48 + j] * scale;
  }
  __syncthreads();
  if (tid < 48) {
    int i = tid;
    float mx = -1e30f;
    for (int j = 0; j < 48; ++j) mx = fmaxf(mx, S[i * 48 + j]);
    float sum = 0.f;
    for (int j = 0; j < 48; ++j) {
      float ev = expf(S[i * 48 + j] - mx);
      S[i * 48 + j] = ev;
      sum += ev;
    }
    float r = 1.f / sum;
    __hip_bfloat16* ap = attn_bf + (size_t)bl * 3072 + i * 64;
    for (int j = 0; j < 48; ++j) ap[j] = __float2bfloat16(S[i * 48 + j] * r);
    for (int j = 48; j < 64; ++j) ap[j] = __float2bfloat16(0.f);
  }
}

// ---------------- A·V via MFMA: aout[b][n][lh*48+c] = sum_d attn[c][d] v[n][d] -----------
__global__ __launch_bounds__(256) void av_mfma(const __hip_bfloat16* __restrict__ attn_bf,
                                               const __hip_bfloat16* __restrict__ qkv,
                                               __hip_bfloat16* __restrict__ aout,
                                               const __hip_bfloat16* __restrict__ zb) {
  __shared__ alignas(16) __hip_bfloat16 la[3072];  // attn [48][64], slot^=(row&7)
  __shared__ alignas(16) __hip_bfloat16 lv[8192];  // V [128 n][64 d], slot^=(row&7)
  int bl = blockIdx.y, b = bl >> 3, lh = bl & 7;
  int n0 = blockIdx.x * 128;
  int tid = threadIdx.x, lane = tid & 63, wv = tid >> 6;
  {
    int r = lane >> 3, sl = lane & 7;
    for (int c = wv; c < 6; c += 4) {  // attn: 6 chunks of 8 rows
      int row = c * 8 + r;
      int sp = sl ^ (row & 7);
      gload16(attn_bf + (size_t)bl * 3072 + row * 64 + sp * 8, la + c * 512);
    }
#pragma unroll
    for (int i = 0; i < 4; ++i) {  // V: 16 chunks of 8 rows
      int c = wv * 4 + i;
      int row = c * 8 + r;
      int sp = sl ^ (row & 7);
      const __hip_bfloat16* src =
          (sp < 6) ? qkv + ((size_t)b * NPIX + n0 + row) * 1152 + lh * 144 + 96 + sp * 8 : zb;
      gload16(src, lv + c * 512);
    }
  }
  __syncthreads();
  int lrow = lane & 15, ko = lane >> 4;
  f32x4 acc[3][2];
#pragma unroll
  for (int cf = 0; cf < 3; ++cf)
#pragma unroll
    for (int nf = 0; nf < 2; ++nf) acc[cf][nf] = {0.f, 0.f, 0.f, 0.f};
  const bf16x8* lav = (const bf16x8*)la;
  const bf16x8* lvv = (const bf16x8*)lv;
#pragma unroll
  for (int ks = 0; ks < 2; ++ks) {
    bf16x8 a[3], vb[2];
#pragma unroll
    for (int cf = 0; cf < 3; ++cf) {
      int c = cf * 16 + lrow;
      a[cf] = lav[c * 8 + ((ks * 4 + ko) ^ (c & 7))];
    }
#pragma unroll
    for (int nf = 0; nf < 2; ++nf) {
      int n = wv * 32 + nf * 16 + lrow;
      vb[nf] = lvv[n * 8 + ((ks * 4 + ko) ^ (n & 7))];
    }
#pragma unroll
    for (int cf = 0; cf < 3; ++cf)
#pragma unroll
      for (int nf = 0; nf < 2; ++nf)
        acc[cf][nf] = __builtin_amdgcn_mfma_f32_16x16x32_bf16(a[cf], vb[nf], acc[cf][nf], 0, 0, 0);
  }
#pragma unroll
  for (int cf = 0; cf < 3; ++cf)
#pragma unroll
    for (int nf = 0; nf < 2; ++nf) {
      int n = n0 + wv * 32 + nf * 16 + lrow;
      int c = cf * 16 + ko * 4;
      *(ushort4*)(aout + ((size_t)b * NPIX + n) * DIM + lh * CH + c) =
          make_ushort4(bfbits(acc[cf][nf][0]), bfbits(acc[cf][nf][1]),
                       bfbits(acc[cf][nf][2]), bfbits(acc[cf][nf][3]));
    }
}

// ---------------- fp32 -> bf16 weight conversion (vec4) ----------------------------------
__global__ __launch_bounds__(256) void wcvt4(const float* __restrict__ w,
                                             __hip_bfloat16* __restrict__ o, int n4) {
  int i = blockIdx.x * 256 + threadIdx.x;
  if (i >= n4) return;
  float4 v = ((const float4*)w)[i];
  ((ushort4*)o)[i] = make_ushort4(bfbits(v.x), bfbits(v.y), bfbits(v.z), bfbits(v.w));
}

extern "C" void kernel_launch(void* const* d_in, const int* in_sizes, int n_in,
                              void* d_out, int out_size, void* d_ws, size_t ws_size,
                              hipStream_t stream) {
  (void)in_sizes; (void)n_in; (void)out_size; (void)ws_size;
  const float* x      = (const float*)d_in[0];
  const float* g1     = (const float*)d_in[1];
  const float* beta1  = (const float*)d_in[2];
  const float* w_qkv  = (const float*)d_in[3];
  const float* b_qkv  = (const float*)d_in[4];
  const float* lsc    = (const float*)d_in[5];
  const float* w_proj = (const float*)d_in[6];
  const float* b_proj = (const float*)d_in[7];
  const float* g2     = (const float*)d_in[8];
  const float* beta2  = (const float*)d_in[9];
  const float* w_ffn1 = (const float*)d_in[10];
  const float* b_ffn1 = (const float*)d_in[11];
  const float* w_ffn2 = (const float*)d_in[12];
  const float* b_ffn2 = (const float*)d_in[13];
  float* out = (float*)d_out;

  // arena (pixel-major bf16 intermediates), max used = 252,788,992 B
  char* ws = (char*)d_ws;
  __hip_bfloat16* xn     = (__hip_bfloat16*)(ws);                 // [16][4096][384] (also yn)
  __hip_bfloat16* qkv    = (__hip_bfloat16*)(ws + 50331648ull);   // [16][4096][1152]
  __hip_bfloat16* hbuf   = (__hip_bfloat16*)(ws + 50331648ull);   // [16][2048][1536] (FFN phase)
  __hip_bfloat16* wffn1b = (__hip_bfloat16*)(ws + 151000064ull);  // converted after AV
  __hip_bfloat16* wffn2b = (__hip_bfloat16*)(ws + 152179712ull);
  __hip_bfloat16* aout   = (__hip_bfloat16*)(ws + 201326592ull);  // [16][4096][384]
  __hip_bfloat16* wqkvb  = (__hip_bfloat16*)(ws + 201326592ull);  // early phase (pre-QK)
  float*          ps     = (float*)(ws + 201326592ull);           // [128][8][2304] (post-QKV)
  float*          pss    = (float*)(ws + 210763776ull);           // [128][8][96]
  const size_t T0 = 251658240ull;
  __hip_bfloat16* attnb  = (__hip_bfloat16*)(ws + T0 + 49152ull); // [128][48][64]
  __hip_bfloat16* zb     = (__hip_bfloat16*)(ws + T0 + 835584ull);// 256B zeros
  __hip_bfloat16* wprojb = (__hip_bfloat16*)(ws + T0 + 835840ull);

  (void)hipMemsetAsync(zb, 0, 256, stream);
  wcvt4<<<432, 256, 0, stream>>>(w_qkv, wqkvb, 110592);
  wcvt4<<<144, 256, 0, stream>>>(w_proj, wprojb, 36864);

  // branch 1: channel attention
  ln_t_kernel<<<dim3(64, 16), 256, 0, stream>>>(x, g1, beta1, xn);
  mfma_gemm<1, 0, 0><<<dim3(32, 9, 16), 256, 0, stream>>>(wqkvb, b_qkv, xn, 4096, 0,
                                                          qkv, 4096, 0, nullptr, 1152, 384);
  qk_a<<<dim3(8, 128), 256, 0, stream>>>(qkv, ps, pss);
  qk_b<<<128, 256, 0, stream>>>(ps, pss, lsc, attnb);
  av_mfma<<<dim3(32, 128), 256, 0, stream>>>(attnb, qkv, aout, zb);
  mfma_gemm<0, 0, 1><<<dim3(32, 3, 16), 256, 0, stream>>>(wprojb, b_proj, aout, 4096, 0,
                                                          d_out, 4096, 0, x, 384, 384);

  // branch 2: FFN (two n-halves to shrink hbuf)
  wcvt4<<<576, 256, 0, stream>>>(w_ffn1, wffn1b, 147456);
  wcvt4<<<576, 256, 0, stream>>>(w_ffn2, wffn2b, 147456);
  ln_t_kernel<<<dim3(64, 16), 256, 0, stream>>>(out, g2, beta2, xn);  // yn
  for (int h = 0; h < 2; ++h) {
    mfma_gemm<1, 1, 0><<<dim3(16, 12, 16), 256, 0, stream>>>(wffn1b, b_ffn1, xn, 4096, h * 2048,
                                                             hbuf, 2048, 0, nullptr, 1536, 384);
    mfma_gemm<0, 0, 1><<<dim3(16, 3, 16), 256, 0, stream>>>(wffn2b, b_ffn2, hbuf, 2048, 0,
                                                            d_out, 4096, h * 2048, (const float*)out,
                                                            384, 1536);
  }
}